// Round 6
// baseline (3323.956 us; speedup 1.0000x reference)
//
#include <hip/hip_runtime.h>

#define D_MODEL 512
#define SEQ     4096
#define BATCH   4
#define M_TOT   (BATCH*SEQ)   // 16384
#define TQ      16            // query rows per attn block
#define KC      256           // key chunk
#define WS_NEEDED ((size_t)M_TOT * D_MODEL * 4)   // node fp32: 32 MiB

// -------- K1: node(fp32) = relu(x @ W^T + b), 64x64 tiles ----------------
extern "C" __global__ __launch_bounds__(256) void proj_kernel(
        const float* __restrict__ x, const float* __restrict__ w,
        const float* __restrict__ bias, float* __restrict__ node) {
    __shared__ float As[32][68];   // k-major, +4 pad
    __shared__ float Bs[32][68];
    const int tid  = threadIdx.x;
    const int row0 = blockIdx.x * 64;
    const int col0 = blockIdx.y * 64;
    const int m0   = (tid & 15) * 4;
    const int n0   = (tid >> 4) * 4;

    float acc[4][4];
    #pragma unroll
    for (int i = 0; i < 4; ++i)
        #pragma unroll
        for (int j = 0; j < 4; ++j) acc[i][j] = 0.0f;

    for (int kc = 0; kc < D_MODEL; kc += 32) {
        // stage: 64 rows x 32 k, transposed into LDS (k-major)
        #pragma unroll
        for (int jj = 0; jj < 2; ++jj) {
            int fi = tid + 256*jj;             // 0..511 float4 slots
            int r  = fi >> 3, c4 = (fi & 7) * 4;
            float4 a4 = *(const float4*)(x + (size_t)(row0 + r)*D_MODEL + kc + c4);
            As[c4+0][r] = a4.x; As[c4+1][r] = a4.y; As[c4+2][r] = a4.z; As[c4+3][r] = a4.w;
            float4 b4 = *(const float4*)(w + (size_t)(col0 + r)*D_MODEL + kc + c4);
            Bs[c4+0][r] = b4.x; Bs[c4+1][r] = b4.y; Bs[c4+2][r] = b4.z; Bs[c4+3][r] = b4.w;
        }
        __syncthreads();
        #pragma unroll
        for (int k = 0; k < 32; ++k) {
            float4 a = *(const float4*)&As[k][m0];
            float4 b = *(const float4*)&Bs[k][n0];
            acc[0][0] += a.x*b.x; acc[0][1] += a.x*b.y; acc[0][2] += a.x*b.z; acc[0][3] += a.x*b.w;
            acc[1][0] += a.y*b.x; acc[1][1] += a.y*b.y; acc[1][2] += a.y*b.z; acc[1][3] += a.y*b.w;
            acc[2][0] += a.z*b.x; acc[2][1] += a.z*b.y; acc[2][2] += a.z*b.z; acc[2][3] += a.z*b.w;
            acc[3][0] += a.w*b.x; acc[3][1] += a.w*b.y; acc[3][2] += a.w*b.z; acc[3][3] += a.w*b.w;
        }
        __syncthreads();
    }
    #pragma unroll
    for (int j = 0; j < 4; ++j) {
        float bv = bias[col0 + n0 + j];
        #pragma unroll
        for (int i = 0; i < 4; ++i) {
            float v = acc[i][j] + bv;
            node[(size_t)(row0 + m0 + i)*D_MODEL + col0 + n0 + j] = v > 0.0f ? v : 0.0f;
        }
    }
}

// -------- K2: flash attention (fp32), TQ rows/block, KC-key chunks --------
extern "C" __global__ __launch_bounds__(256) void attn_kernel(
        const float* __restrict__ node, float* __restrict__ outp) {
    __shared__ float Qs[TQ][516];     // +4 pad; row stride 2064 B (16B-aligned)
    __shared__ float Sc[KC][TQ];      // kl-major scores -> probabilities
    __shared__ float red[256];
    __shared__ float mrow[TQ], lrow[TQ], arow[TQ], mnew[TQ];

    const int tid = threadIdx.x;      // 256
    const int li  = tid & 15;         // reduction lane within q-row group
    const int qi  = tid >> 4;         // q-row for reduction phases (0..15)
    const int bb  = blockIdx.y;
    const int q0  = blockIdx.x * TQ;

    const float* nodeb = node + (size_t)bb * SEQ * D_MODEL;

    for (int idx = tid; idx < TQ*512; idx += 256) {
        int q = idx >> 9, d = idx & 511;
        Qs[q][d] = nodeb[(size_t)(q0 + q)*D_MODEL + d];
    }
    if (tid < TQ) { mrow[tid] = -3.0e38f; lrow[tid] = 0.0f; }

    float oacc[TQ][2];
    #pragma unroll
    for (int q = 0; q < TQ; ++q) { oacc[q][0] = 0.0f; oacc[q][1] = 0.0f; }
    __syncthreads();

    for (int kc = 0; kc < SEQ; kc += KC) {
        __syncthreads();   // prev chunk's Sc reads done before overwrite

        // ---- Phase A: scores, one key per thread, 16 q-rows ----
        {
            float acc[TQ];
            #pragma unroll
            for (int q = 0; q < TQ; ++q) acc[q] = 0.0f;
            const float* krow = nodeb + (size_t)(kc + tid)*D_MODEL;
            for (int d = 0; d < 512; d += 4) {
                float4 kv = *(const float4*)(krow + d);
                #pragma unroll
                for (int q = 0; q < TQ; ++q) {
                    float4 qv = *(const float4*)&Qs[q][d];
                    acc[q] += kv.x*qv.x + kv.y*qv.y + kv.z*qv.z + kv.w*qv.w;
                }
            }
            #pragma unroll
            for (int q = 0; q < TQ; ++q) Sc[tid][q] = acc[q];
        }
        __syncthreads();

        // ---- Phase B1: row max (16 threads per row, 16 entries each) ----
        {
            float lm = -3.0e38f;
            #pragma unroll
            for (int i = 0; i < KC/16; ++i) lm = fmaxf(lm, Sc[li*(KC/16) + i][qi]);
            red[tid] = lm;
        }
        for (int off = 8; off >= 1; off >>= 1) {
            __syncthreads();
            if (li < off) red[tid] = fmaxf(red[tid], red[tid + off]);
        }
        __syncthreads();
        if (tid < TQ) {
            float mo = mrow[tid];
            float mn = fmaxf(mo, red[tid*16]);
            mnew[tid] = mn;
            arow[tid] = __expf(mo - mn);
            mrow[tid] = mn;
        }
        __syncthreads();

        // ---- Phase B2: exponentiate + row sum ----
        {
            float mn = mnew[qi];
            float ls = 0.0f;
            #pragma unroll
            for (int i = 0; i < KC/16; ++i) {
                int idx = li*(KC/16) + i;
                float p = __expf(Sc[idx][qi] - mn);
                Sc[idx][qi] = p;
                ls += p;
            }
            red[tid] = ls;
        }
        for (int off = 8; off >= 1; off >>= 1) {
            __syncthreads();
            if (li < off) red[tid] = red[tid] + red[tid + off];
        }
        __syncthreads();
        if (tid < TQ) lrow[tid] = lrow[tid]*arow[tid] + red[tid*16];

        // ---- Phase C: rescale O, accumulate P*V (thread owns d-pair 2*tid) ----
        {
            float a[TQ];
            #pragma unroll
            for (int q = 0; q < TQ; ++q) a[q] = arow[q];
            #pragma unroll
            for (int q = 0; q < TQ; ++q) { oacc[q][0] *= a[q]; oacc[q][1] *= a[q]; }
        }
        {
            const float* vbase = nodeb + (size_t)kc*D_MODEL + 2*tid;
            for (int kl = 0; kl < KC; ++kl) {
                float2 nv = *(const float2*)(vbase + (size_t)kl*D_MODEL);
                float4 pA = *(const float4*)&Sc[kl][0];
                float4 pB = *(const float4*)&Sc[kl][4];
                float4 pC = *(const float4*)&Sc[kl][8];
                float4 pD = *(const float4*)&Sc[kl][12];
                oacc[0][0]  += pA.x*nv.x; oacc[0][1]  += pA.x*nv.y;
                oacc[1][0]  += pA.y*nv.x; oacc[1][1]  += pA.y*nv.y;
                oacc[2][0]  += pA.z*nv.x; oacc[2][1]  += pA.z*nv.y;
                oacc[3][0]  += pA.w*nv.x; oacc[3][1]  += pA.w*nv.y;
                oacc[4][0]  += pB.x*nv.x; oacc[4][1]  += pB.x*nv.y;
                oacc[5][0]  += pB.y*nv.x; oacc[5][1]  += pB.y*nv.y;
                oacc[6][0]  += pB.z*nv.x; oacc[6][1]  += pB.z*nv.y;
                oacc[7][0]  += pB.w*nv.x; oacc[7][1]  += pB.w*nv.y;
                oacc[8][0]  += pC.x*nv.x; oacc[8][1]  += pC.x*nv.y;
                oacc[9][0]  += pC.y*nv.x; oacc[9][1]  += pC.y*nv.y;
                oacc[10][0] += pC.z*nv.x; oacc[10][1] += pC.z*nv.y;
                oacc[11][0] += pC.w*nv.x; oacc[11][1] += pC.w*nv.y;
                oacc[12][0] += pD.x*nv.x; oacc[12][1] += pD.x*nv.y;
                oacc[13][0] += pD.y*nv.x; oacc[13][1] += pD.y*nv.y;
                oacc[14][0] += pD.z*nv.x; oacc[14][1] += pD.z*nv.y;
                oacc[15][0] += pD.w*nv.x; oacc[15][1] += pD.w*nv.y;
            }
        }
    }

    __syncthreads();   // lrow final values visible
    #pragma unroll
    for (int q = 0; q < TQ; ++q) {
        float inv = 1.0f / lrow[q];
        float2 v; v.x = oacc[q][0]*inv; v.y = oacc[q][1]*inv;
        *(float2*)(outp + ((size_t)bb*SEQ + q0 + q)*D_MODEL + 2*tid) = v;
    }
}

extern "C" void kernel_launch(void* const* d_in, const int* in_sizes, int n_in,
                              void* d_out, int out_size, void* d_ws, size_t ws_size,
                              hipStream_t stream) {
    const float* x = (const float*)d_in[0];
    const float* w = (const float*)d_in[1];
    const float* b = (const float*)d_in[2];
    float* out  = (float*)d_out;
    float* node = (float*)d_ws;

    // canary (safe size under any dtype interpretation): if kernels never
    // write d_out, absmax ~= 48.5-ish instead of max|ref|
    (void)hipMemsetAsync(d_out, 0x42, (size_t)out_size * 2, stream);

    if (d_ws == 0 || ws_size < WS_NEEDED) {
        (void)hipMemsetAsync(d_out, 0x4F, (size_t)out_size * 2, stream);
        return;
    }

    (void)hipGetLastError();
    proj_kernel<<<dim3(M_TOT/64, D_MODEL/64), dim3(256), 0, stream>>>(x, w, b, node);
    hipError_t ep = hipGetLastError();
    attn_kernel<<<dim3(SEQ/TQ, BATCH), dim3(256), 0, stream>>>(node, out);
    hipError_t ef = hipGetLastError();

    if (ep != hipSuccess) {
        (void)hipMemsetAsync(d_out, 0x49, (size_t)out_size * 2, stream);
    } else if (ef != hipSuccess) {
        (void)hipMemsetAsync(d_out, 0x4B, (size_t)out_size * 2, stream);
    }
}

// Round 7
// 616.732 us; speedup vs baseline: 5.3896x; 5.3896x over previous
//
#include <hip/hip_runtime.h>

#define D_MODEL 512
#define SEQ     4096
#define BATCH   4
#define M_TOT   (BATCH*SEQ)   // 16384
#define WS_NEEDED ((size_t)2 * M_TOT * D_MODEL * 2)   // node_bf + nodeT_bf: 32 MiB

typedef float  f32x4  __attribute__((ext_vector_type(4)));
typedef __bf16 bf16x8 __attribute__((ext_vector_type(8)));

union FU { float f; unsigned int u; };
__device__ __forceinline__ unsigned short f_to_bf16(float f) {
    FU c; c.f = f;
    unsigned int r = c.u + 0x7fffu + ((c.u >> 16) & 1u);   // RNE
    return (unsigned short)(r >> 16);
}

// -------- K1: node_bf = relu(x @ W^T + b) (bf16), + transposed copy --------
extern "C" __global__ __launch_bounds__(256) void proj_kernel(
        const float* __restrict__ x, const float* __restrict__ w,
        const float* __restrict__ bias,
        unsigned short* __restrict__ node_bf, unsigned short* __restrict__ nodeT_bf) {
    __shared__ float As[32][68];   // k-major, +4 pad
    __shared__ float Bs[32][68];
    const int tid  = threadIdx.x;
    const int row0 = blockIdx.x * 64;
    const int col0 = blockIdx.y * 64;
    const int m0   = (tid & 15) * 4;
    const int n0   = (tid >> 4) * 4;

    float acc[4][4];
    #pragma unroll
    for (int i = 0; i < 4; ++i)
        #pragma unroll
        for (int j = 0; j < 4; ++j) acc[i][j] = 0.0f;

    for (int kc = 0; kc < D_MODEL; kc += 32) {
        #pragma unroll
        for (int jj = 0; jj < 2; ++jj) {
            int fi = tid + 256*jj;
            int r  = fi >> 3, c4 = (fi & 7) * 4;
            float4 a4 = *(const float4*)(x + (size_t)(row0 + r)*D_MODEL + kc + c4);
            As[c4+0][r] = a4.x; As[c4+1][r] = a4.y; As[c4+2][r] = a4.z; As[c4+3][r] = a4.w;
            float4 b4 = *(const float4*)(w + (size_t)(col0 + r)*D_MODEL + kc + c4);
            Bs[c4+0][r] = b4.x; Bs[c4+1][r] = b4.y; Bs[c4+2][r] = b4.z; Bs[c4+3][r] = b4.w;
        }
        __syncthreads();
        #pragma unroll
        for (int k = 0; k < 32; ++k) {
            float4 a = *(const float4*)&As[k][m0];
            float4 b = *(const float4*)&Bs[k][n0];
            acc[0][0] += a.x*b.x; acc[0][1] += a.x*b.y; acc[0][2] += a.x*b.z; acc[0][3] += a.x*b.w;
            acc[1][0] += a.y*b.x; acc[1][1] += a.y*b.y; acc[1][2] += a.y*b.z; acc[1][3] += a.y*b.w;
            acc[2][0] += a.z*b.x; acc[2][1] += a.z*b.y; acc[2][2] += a.z*b.z; acc[2][3] += a.z*b.w;
            acc[3][0] += a.w*b.x; acc[3][1] += a.w*b.y; acc[3][2] += a.w*b.z; acc[3][3] += a.w*b.w;
        }
        __syncthreads();
    }
    #pragma unroll
    for (int j = 0; j < 4; ++j) {
        float bv = bias[col0 + n0 + j];
        #pragma unroll
        for (int i = 0; i < 4; ++i) {
            float v = acc[i][j] + bv;
            v = v > 0.0f ? v : 0.0f;
            unsigned short us = f_to_bf16(v);
            int row = row0 + m0 + i, col = col0 + n0 + j;
            node_bf[(size_t)row*D_MODEL + col] = us;
            int b = row >> 12, si = row & 4095;
            nodeT_bf[((size_t)(b*D_MODEL + col))*SEQ + si] = us;
        }
    }
}

// -------- K2: flash attention via MFMA, out(fp32) --------
// LDS: 33280 + 20480 + 5120 = 58880 B (< 64 KiB)
extern "C" __global__ __launch_bounds__(256) void flash_kernel(
        const unsigned short* __restrict__ node,
        const unsigned short* __restrict__ nodeT,
        float* __restrict__ out) {
    __shared__ short Ks[32][520];     // K-tile (keys x d), +8 pad
    __shared__ short Vt[256][40];     // half V^T tile (256 d x 32 keys), +8 pad
    __shared__ short Ps[4][16][40];   // per-wave P tile (qrow x key), +8 pad
    const int tid  = threadIdx.x;
    const int lane = tid & 63;
    const int wv   = tid >> 6;
    const int lr   = lane & 15;
    const int quad = lane >> 4;
    const int bb   = blockIdx.y;
    const int q0   = blockIdx.x * 64;

    const unsigned short* nb  = node  + (size_t)bb * SEQ * D_MODEL;
    const unsigned short* ntb = nodeT + (size_t)bb * D_MODEL * SEQ;

    // Q fragments: A[m=lr][k = t*32 + quad*8 + j]
    bf16x8 qf[16];
    const int qrow = q0 + wv*16 + lr;
    #pragma unroll
    for (int t = 0; t < 16; ++t)
        qf[t] = *reinterpret_cast<const bf16x8*>(&nb[(size_t)qrow*D_MODEL + t*32 + quad*8]);

    f32x4 o[32];
    #pragma unroll
    for (int n = 0; n < 32; ++n) o[n] = (f32x4){0.f,0.f,0.f,0.f};
    float m_run[4] = {-3.0e38f,-3.0e38f,-3.0e38f,-3.0e38f};
    float l_run[4] = {0.f,0.f,0.f,0.f};

    for (int kt = 0; kt < SEQ/32; ++kt) {
        // stage K tile (32 keys x 512 d)
        #pragma unroll
        for (int p = 0; p < 8; ++p) {
            int c = p*256 + tid;
            int r = c >> 6, c8 = (c & 63) * 8;
            *reinterpret_cast<int4*>(&Ks[r][c8]) =
                *reinterpret_cast<const int4*>(&nb[(size_t)(kt*32 + r)*D_MODEL + c8]);
        }
        // stage V^T half 0 (d = 0..255)
        #pragma unroll
        for (int p = 0; p < 4; ++p) {
            int c = p*256 + tid;
            int d = c >> 2, c8 = (c & 3) * 8;
            *reinterpret_cast<int4*>(&Vt[d][c8]) =
                *reinterpret_cast<const int4*>(&ntb[(size_t)d*SEQ + kt*32 + c8]);
        }
        __syncthreads();

        // S = Q K^T (per wave: 16 qrows x 32 keys)
        f32x4 sacc[2];
        sacc[0] = (f32x4){0.f,0.f,0.f,0.f};
        sacc[1] = (f32x4){0.f,0.f,0.f,0.f};
        #pragma unroll
        for (int t = 0; t < 16; ++t) {
            #pragma unroll
            for (int s = 0; s < 2; ++s) {
                bf16x8 kb = *reinterpret_cast<const bf16x8*>(&Ks[s*16 + lr][t*32 + quad*8]);
                sacc[s] = __builtin_amdgcn_mfma_f32_16x16x32_bf16(qf[t], kb, sacc[s], 0, 0, 0);
            }
        }

        // online softmax; C/D layout: row = quad*4+r, col = lr (m89)
        float alpha[4];
        #pragma unroll
        for (int r = 0; r < 4; ++r) {
            float mx = fmaxf(sacc[0][r], sacc[1][r]);
            #pragma unroll
            for (int off = 1; off < 16; off <<= 1)
                mx = fmaxf(mx, __shfl_xor(mx, off));
            float mnew = fmaxf(m_run[r], mx);
            alpha[r] = __expf(m_run[r] - mnew);
            float p0 = __expf(sacc[0][r] - mnew);
            float p1 = __expf(sacc[1][r] - mnew);
            m_run[r] = mnew;
            float rs = p0 + p1;
            #pragma unroll
            for (int off = 1; off < 16; off <<= 1)
                rs += __shfl_xor(rs, off);
            l_run[r] = l_run[r]*alpha[r] + rs;
            Ps[wv][quad*4 + r][lr]      = (short)f_to_bf16(p0);
            Ps[wv][quad*4 + r][16 + lr] = (short)f_to_bf16(p1);
        }
        #pragma unroll
        for (int n = 0; n < 32; ++n) {
            #pragma unroll
            for (int r = 0; r < 4; ++r) o[n][r] *= alpha[r];
        }
        // P fragment: A[m=lr][k=quad*8+j], reused across both PV halves
        bf16x8 pa = *reinterpret_cast<const bf16x8*>(&Ps[wv][lr][quad*8]);

        // PV half 0: d-blocks 0..15
        #pragma unroll
        for (int n = 0; n < 16; ++n) {
            bf16x8 vb = *reinterpret_cast<const bf16x8*>(&Vt[n*16 + lr][quad*8]);
            o[n] = __builtin_amdgcn_mfma_f32_16x16x32_bf16(pa, vb, o[n], 0, 0, 0);
        }
        __syncthreads();

        // stage V^T half 1 (d = 256..511)
        #pragma unroll
        for (int p = 0; p < 4; ++p) {
            int c = p*256 + tid;
            int d = c >> 2, c8 = (c & 3) * 8;
            *reinterpret_cast<int4*>(&Vt[d][c8]) =
                *reinterpret_cast<const int4*>(&ntb[(size_t)(256 + d)*SEQ + kt*32 + c8]);
        }
        __syncthreads();

        // PV half 1: d-blocks 16..31
        #pragma unroll
        for (int n = 16; n < 32; ++n) {
            bf16x8 vb = *reinterpret_cast<const bf16x8*>(&Vt[(n-16)*16 + lr][quad*8]);
            o[n] = __builtin_amdgcn_mfma_f32_16x16x32_bf16(pa, vb, o[n], 0, 0, 0);
        }
        __syncthreads();
    }

    // epilogue: out = O / l (fp32)
    #pragma unroll
    for (int r = 0; r < 4; ++r) {
        float inv = 1.0f / l_run[r];
        int row = q0 + wv*16 + quad*4 + r;
        float* obase = out + ((size_t)bb * SEQ + row) * D_MODEL;
        #pragma unroll
        for (int n = 0; n < 32; ++n)
            obase[n*16 + lr] = o[n][r] * inv;
    }
}

extern "C" void kernel_launch(void* const* d_in, const int* in_sizes, int n_in,
                              void* d_out, int out_size, void* d_ws, size_t ws_size,
                              hipStream_t stream) {
    const float* x = (const float*)d_in[0];
    const float* w = (const float*)d_in[1];
    const float* b = (const float*)d_in[2];
    float* out = (float*)d_out;
    unsigned short* node_bf  = (unsigned short*)d_ws;
    unsigned short* nodeT_bf = node_bf + (size_t)M_TOT * D_MODEL;
    const size_t out_bytes = (size_t)out_size * 4;

    // canary: if nothing below writes d_out, absmax ~= 48.6
    (void)hipMemsetAsync(d_out, 0x42, out_bytes, stream);

    if (d_ws == 0 || ws_size < WS_NEEDED) {
        (void)hipMemsetAsync(d_out, 0x4F, out_bytes, stream);   // ws sentinel
        return;
    }

    (void)hipGetLastError();
    proj_kernel<<<dim3(M_TOT/64, D_MODEL/64), dim3(256), 0, stream>>>(x, w, b, node_bf, nodeT_bf);
    hipError_t ep = hipGetLastError();
    flash_kernel<<<dim3(SEQ/64, BATCH), dim3(256), 0, stream>>>(node_bf, nodeT_bf, out);
    hipError_t ef = hipGetLastError();

    if (ep != hipSuccess) {
        (void)hipMemsetAsync(d_out, 0x49, out_bytes, stream);   // proj launch fail
    } else if (ef != hipSuccess) {
        (void)hipMemsetAsync(d_out, 0x4B, out_bytes, stream);   // flash launch fail
    }
}